// Round 17
// baseline (227.198 us; speedup 1.0000x reference)
//
#include <hip/hip_runtime.h>
#include <hip/hip_bf16.h>

typedef __attribute__((ext_vector_type(8))) short short8;
typedef __attribute__((ext_vector_type(4))) float f32x4;
typedef __attribute__((ext_vector_type(16))) float f32x16;
typedef unsigned short u16;

#define EPSV 1e-5f

__device__ __forceinline__ u16 f2bf(float f) {
    __hip_bfloat16 h = __float2bfloat16(f);
    return *reinterpret_cast<u16*>(&h);
}

#define GLOAD_LDS16(g, l)                                                      \
    __builtin_amdgcn_global_load_lds(                                          \
        (const __attribute__((address_space(1))) void*)(g),                    \
        (__attribute__((address_space(3))) void*)(l), 16, 0, 0)

// ---------------- fused NCHW fp32 -> [C/32][N][H][W][32] bf16 (x and s) ----------------
__global__ void cvt_fused_kernel(const float* __restrict__ x, u16* __restrict__ xb,
                                 const float* __restrict__ s, u16* __restrict__ sb) {
    int b = blockIdx.x;
    const float* src; u16* dst; int C, H, W, u;
    if (b < 4096) { src = x; dst = xb; C = 128; H = 64;  W = 64;  u = b * 256 + threadIdx.x; if (u >= 1048576) return; }
    else          { src = s; dst = sb; C = 64;  H = 128; W = 128; u = (b - 4096) * 256 + threadIdx.x; if (u >= 2097152) return; }
    int kb = u & 3;
    int p  = u >> 2;
    int xx = p % W;  p /= W;
    int yy = p % H;  p /= H;
    int n  = p & 15;
    int cc = p >> 4;
    short8 v;
#pragma unroll
    for (int j = 0; j < 8; ++j)
        v[j] = (short)f2bf(src[(((size_t)n * C + cc * 32 + kb * 8 + j) * H + yy) * W + xx]);
    *(short8*)(dst + ((((size_t)cc * 16 + n) * H + yy) * W + xx) * 32 + kb * 8) = v;
}

// ---------------- fused weight repack ----------------
// w1 (16x16 frags, unchanged): unit (((cc*8+bt)*9+t)*4+ciC)*64+l
// ws/w2 (32x32 frags):         unit ((((bt2*9+t)*4+ciC)*2+kin)*64+l
//   element: w[co=bt2*32+(l&31)][ci=ciC*32+kin*16+(l>>5)*8+e]
__global__ void repack_fused_kernel(const float* __restrict__ w1, const float* __restrict__ ws,
                                    const float* __restrict__ w2, u16* __restrict__ wf1,
                                    u16* __restrict__ wfS, u16* __restrict__ wf2) {
    int b = blockIdx.x;
    if (b < 288) {
        int u = b * 256 + threadIdx.x;
        if (u >= 4 * 8 * 9 * 4 * 64) return;
        int l = u & 63;
        int r = u >> 6;
        int ciC = r & 3;  r >>= 2;
        int t   = r % 9;  r /= 9;
        int bt  = r & 7;
        int cc  = r >> 3;
        int co  = (bt >> 1) * 128 + cc * 32 + (bt & 1) * 16 + (l & 15);
        int ci0 = ciC * 32 + (l >> 4) * 8;
        short8 v;
#pragma unroll
        for (int e = 0; e < 8; ++e)
            v[e] = (short)f2bf(w1[((size_t)co * 128 + ci0 + e) * 9 + t]);
        *(short8*)(wf1 + (size_t)u * 8) = v;
    } else {
        int g = b - 288;                      // 0..71: g<36 -> ws, else w2
        const float* w = (g < 36) ? ws : w2;
        u16* wf        = (g < 36) ? wfS : wf2;
        int u = (g % 36) * 256 + threadIdx.x;
        if (u >= 2 * 9 * 4 * 2 * 64) return;  // 9216 units
        int l = u & 63;
        int r = u >> 6;
        int kin = r & 1;  r >>= 1;
        int ciC = r & 3;  r >>= 2;
        int t   = r % 9;
        int bt2 = r / 9;
        int co  = bt2 * 32 + (l & 31);
        int ci0 = ciC * 32 + kin * 16 + (l >> 5) * 8;
        short8 v;
#pragma unroll
        for (int e = 0; e < 8; ++e)
            v[e] = (short)f2bf(w[((size_t)co * 128 + ci0 + e) * 9 + t]);
        *(short8*)(wf + (size_t)u * 8) = v;
    }
}

// ---------------- conv1 + BN + ReLU + Haar IDWT (MFMA, LDS weight staging) ----------------
// Round-10/13 proven config (~81us): counted-vmcnt weight dbuf; setprio REMOVED
// (R14 A/B: +1us regression).
__global__ __launch_bounds__(256, 2)
void conv1_mfma_kernel(const u16* __restrict__ inb, const u16* __restrict__ wf,
                       const float* __restrict__ bb, const float* __restrict__ gg,
                       const float* __restrict__ bee, const float* __restrict__ mm,
                       const float* __restrict__ vv, u16* __restrict__ ob) {
    const int tile = blockIdx.x;              // 4x x 8y = 32
    const int cc   = blockIdx.y;              // 4 base-c chunks
    const int n    = blockIdx.z;
    const int x0   = (tile & 3) * 16;
    const int y0   = (tile >> 2) * 8;
    const int tid  = threadIdx.x;
    const int lane = tid & 63;
    const int wid  = tid >> 6;
    const int wm   = wid >> 1;
    const int wc   = wid & 1;
    const int kb   = lane >> 4;
    const int xl   = lane & 15;

    __shared__ float4 lds4[720];              // input: 10 x 18 x 32 bf16, swizzled
    __shared__ float4 wlds[2][1536];          // weights: [buf][(bt*3+dy)*64 + lane]
    const short8* ldsr  = (const short8*)lds4;
    const short8* wldsr = (const short8*)wlds;

    f32x4 acc[4][4];
#pragma unroll
    for (int j = 0; j < 4; ++j)
#pragma unroll
        for (int q = 0; q < 4; ++q) acc[j][q] = (f32x4){0.f, 0.f, 0.f, 0.f};

    float4 sreg[3];
    auto load_stage = [&](int ciC) {
#pragma unroll
        for (int p = 0; p < 3; ++p) {
            int e = p * 256 + tid;
            float4 v = make_float4(0.f, 0.f, 0.f, 0.f);
            if (e < 720) {
                int pix = e >> 2, ke = e & 3;
                int yy = pix / 18;
                int xx = pix - yy * 18;
                int gy = y0 - 1 + yy, gx = x0 - 1 + xx;
                if ((unsigned)gy < 64u && (unsigned)gx < 64u)
                    v = *(const float4*)(inb + ((((size_t)ciC * 16 + n) * 64 + gy) * 64 + gx) * 32 + ke * 8);
            }
            sreg[p] = v;
        }
    };
    auto write_stage = [&]() {
#pragma unroll
        for (int p = 0; p < 3; ++p) {
            int e = p * 256 + tid;
            if (e < 720) lds4[e ^ ((e >> 2) & 7)] = sreg[p];
        }
    };
    auto stage_w = [&](int ciC, int dx, int buf) {
#pragma unroll
        for (int i = 0; i < 6; ++i) {
            int seg = wid * 6 + i;            // seg = bt*3 + dy
            int bt  = seg / 3;
            int dy  = seg - bt * 3;
            int t   = dy * 3 + dx;
            const u16* gp = wf + (size_t)((cc * 8 + bt) * 9 + t) * 2048 + ciC * 512 + lane * 8;
            GLOAD_LDS16(gp, &wlds[buf][seg * 64]);
        }
    };

    load_stage(0);
    stage_w(0, 0, 0);
    for (int ciC = 0; ciC < 4; ++ciC) {
        write_stage();
        asm volatile("s_waitcnt lgkmcnt(0)" ::: "memory");
        __builtin_amdgcn_s_barrier();
        __builtin_amdgcn_sched_barrier(0);
        if (ciC < 3) load_stage(ciC + 1);
#pragma unroll
        for (int dx = 0; dx < 3; ++dx) {
            const int cur = (ciC + dx) & 1;
            if (dx == 0) {
                if (ciC < 3) asm volatile("s_waitcnt vmcnt(3)" ::: "memory");
                else         asm volatile("s_waitcnt vmcnt(0)" ::: "memory");
            } else {
                asm volatile("s_waitcnt vmcnt(0)" ::: "memory");
            }
            __builtin_amdgcn_sched_barrier(0);
            __builtin_amdgcn_s_barrier();
            __builtin_amdgcn_sched_barrier(0);
            if (dx < 2)        stage_w(ciC, dx + 1, cur ^ 1);
            else if (ciC < 3)  stage_w(ciC + 1, 0, cur ^ 1);

            short8 a[6];
#pragma unroll
            for (int r = 0; r < 6; ++r) {
                int pix = (wm * 4 + r) * 18 + xl + dx;
                int e = pix * 4 + kb;
                a[r] = ldsr[e ^ ((e >> 2) & 7)];
            }
#pragma unroll
            for (int dy = 0; dy < 3; ++dy) {
                short8 b[4];
#pragma unroll
                for (int q = 0; q < 4; ++q) {
                    int bt = q * 2 + wc;
                    b[q] = wldsr[cur * 1536 + (bt * 3 + dy) * 64 + lane];
                }
#pragma unroll
                for (int j = 0; j < 4; ++j)
#pragma unroll
                    for (int q = 0; q < 4; ++q)
                        acc[j][q] = __builtin_amdgcn_mfma_f32_16x16x32_bf16(a[j + dy], b[q], acc[j][q], 0, 0, 0);
            }
        }
        __builtin_amdgcn_s_barrier();
    }

    float invq[4], shq[4];
#pragma unroll
    for (int q = 0; q < 4; ++q) {
        int co  = q * 128 + cc * 32 + wc * 16 + xl;
        float inv = gg[co] / sqrtf(vv[co] + EPSV);
        invq[q] = inv;
        shq[q]  = bb[co] * inv + bee[co] - mm[co] * inv;
    }
    const int c32 = wc * 16 + xl;
#pragma unroll
    for (int j = 0; j < 4; ++j) {
        int y = y0 + wm * 4 + j;
#pragma unroll
        for (int i = 0; i < 4; ++i) {
            float A_ = fmaxf(acc[j][0][i] * invq[0] + shq[0], 0.f);
            float H_ = fmaxf(acc[j][1][i] * invq[1] + shq[1], 0.f);
            float V_ = fmaxf(acc[j][2][i] * invq[2] + shq[2], 0.f);
            float D_ = fmaxf(acc[j][3][i] * invq[3] + shq[3], 0.f);
            float p00 = (A_ + H_ + V_ + D_) * 0.5f;
            float p01 = (A_ + H_ - V_ - D_) * 0.5f;
            float p10 = (A_ - H_ + V_ - D_) * 0.5f;
            float p11 = (A_ - H_ - V_ + D_) * 0.5f;
            int oy = 2 * y, ox = 2 * (x0 + kb * 4 + i);
            size_t base = ((((size_t)cc * 16 + n) * 128 + oy) * 128 + ox) * 32 + c32;
            ob[base]            = f2bf(p00);
            ob[base + 32]       = f2bf(p01);
            ob[base + 128 * 32] = f2bf(p10);
            ob[base + 128 * 32 + 32] = f2bf(p11);
        }
    }
}

// ---------------- generic 128ci -> 64co conv + BN + ReLU (32x32x16 MFMA) ----------------
// Wave = 32 pixels (16x x 2y) x 64 co (2 groups of 32). A: row=lane&31 (pixel),
// k=(lane>>5)*8+e. B: col=lane&31 (co), same k. C/D: col=lane&31 (co),
// row=(reg&3)+8*(reg>>2)+4*(lane>>5) (pixel) [HW-verified, learn_hip m74/m101].
template <bool FP32OUT>
__global__ __launch_bounds__(256, 2)
void convg_mfma_kernel(const u16* __restrict__ inb, const u16* __restrict__ wf,
                       const float* __restrict__ bb, const float* __restrict__ gg,
                       const float* __restrict__ bee, const float* __restrict__ mm,
                       const float* __restrict__ vv, u16* __restrict__ ob,
                       float* __restrict__ of) {
    const int tile = blockIdx.x;              // 8x x 16y = 128
    const int n    = blockIdx.y;
    const int x0   = (tile & 7) * 16;
    const int y0   = (tile >> 3) * 8;
    const int tid  = threadIdx.x;
    const int lane = tid & 63;
    const int wid  = tid >> 6;                // wave: rows wid*2, wid*2+1
    const int row  = lane & 31;               // A-side pixel index
    const int kh   = lane >> 5;               // k-half
    const int px   = row & 15;
    const int py   = row >> 4;

    __shared__ float4 lds4[720];              // 10 x 18 x 32 bf16, swizzled
    const short8* ldsr = (const short8*)lds4;

    f32x16 acc[2];
#pragma unroll
    for (int b2 = 0; b2 < 2; ++b2)
#pragma unroll
        for (int e = 0; e < 16; ++e) acc[b2][e] = 0.f;

    float4 sreg[3];
    auto load_stage = [&](int ciC) {
#pragma unroll
        for (int p = 0; p < 3; ++p) {
            int e = p * 256 + tid;
            float4 v = make_float4(0.f, 0.f, 0.f, 0.f);
            if (e < 720) {
                int pix = e >> 2, ke = e & 3;
                int yy = pix / 18;
                int xx = pix - yy * 18;
                int gy = y0 - 1 + yy, gx = x0 - 1 + xx;
                if ((unsigned)gy < 128u && (unsigned)gx < 128u)
                    v = *(const float4*)(inb + ((((size_t)ciC * 16 + n) * 128 + gy) * 128 + gx) * 32 + ke * 8);
            }
            sreg[p] = v;
        }
    };
    auto write_stage = [&]() {
#pragma unroll
        for (int p = 0; p < 3; ++p) {
            int e = p * 256 + tid;
            if (e < 720) lds4[e ^ ((e >> 2) & 7)] = sreg[p];
        }
    };

    load_stage(0);
    for (int ciC = 0; ciC < 4; ++ciC) {
        write_stage();
        __syncthreads();
        if (ciC < 3) load_stage(ciC + 1);
#pragma unroll
        for (int dx = 0; dx < 3; ++dx) {
            short8 a[3][2];                    // [dy][kin]
#pragma unroll
            for (int dy = 0; dy < 3; ++dy)
#pragma unroll
                for (int kin = 0; kin < 2; ++kin) {
                    int pix = (wid * 2 + py + dy) * 18 + px + dx;
                    int e = pix * 4 + kin * 2 + kh;
                    a[dy][kin] = ldsr[e ^ ((e >> 2) & 7)];
                }
#pragma unroll
            for (int dy = 0; dy < 3; ++dy) {
                const int t = dy * 3 + dx;
#pragma unroll
                for (int kin = 0; kin < 2; ++kin)
#pragma unroll
                    for (int b2 = 0; b2 < 2; ++b2) {
                        short8 b = *(const short8*)(wf + ((size_t)((((b2 * 9 + t) * 4 + ciC) * 2) + kin) * 64 + lane) * 8);
                        acc[b2] = __builtin_amdgcn_mfma_f32_32x32x16_bf16(a[dy][kin], b, acc[b2], 0, 0, 0);
                    }
            }
        }
        __syncthreads();
    }

#pragma unroll
    for (int b2 = 0; b2 < 2; ++b2) {
        int co = b2 * 32 + (lane & 31);       // C/D col = lane&31
        float inv = gg[co] / sqrtf(vv[co] + EPSV);
        float sh  = bb[co] * inv + bee[co] - mm[co] * inv;
#pragma unroll
        for (int g = 0; g < 4; ++g) {
            int rbase = g * 8 + kh * 4;       // row = rbase + i, i=0..3
            int xg = x0 + (rbase & 15);       // i adds 0..3 along x
            int yg = y0 + wid * 2 + (rbase >> 4);
            if (FP32OUT) {
                float4 v4;
                v4.x = fmaxf(acc[b2][g * 4 + 0] * inv + sh, 0.f);
                v4.y = fmaxf(acc[b2][g * 4 + 1] * inv + sh, 0.f);
                v4.z = fmaxf(acc[b2][g * 4 + 2] * inv + sh, 0.f);
                v4.w = fmaxf(acc[b2][g * 4 + 3] * inv + sh, 0.f);
                *(float4*)&of[(((size_t)n * 64 + co) * 128 + yg) * 128 + xg] = v4;
            } else {
#pragma unroll
                for (int i = 0; i < 4; ++i) {
                    float val = fmaxf(acc[b2][g * 4 + i] * inv + sh, 0.f);
                    ob[((((size_t)b2 * 16 + n) * 128 + yg) * 128 + xg + i) * 32 + (co & 31)] = f2bf(val);
                }
            }
        }
    }
}

extern "C" void kernel_launch(void* const* d_in, const int* in_sizes, int n_in,
                              void* d_out, int out_size, void* d_ws, size_t ws_size,
                              hipStream_t stream) {
    const float* x   = (const float*)d_in[0];
    const float* s   = (const float*)d_in[1];
    const float* w1  = (const float*)d_in[2];
    const float* b1  = (const float*)d_in[3];
    const float* g1  = (const float*)d_in[4];
    const float* be1 = (const float*)d_in[5];
    const float* m1  = (const float*)d_in[6];
    const float* v1  = (const float*)d_in[7];
    const float* wsw = (const float*)d_in[8];
    const float* bs  = (const float*)d_in[9];
    const float* gs  = (const float*)d_in[10];
    const float* bes = (const float*)d_in[11];
    const float* ms  = (const float*)d_in[12];
    const float* vs  = (const float*)d_in[13];
    const float* w2  = (const float*)d_in[14];
    const float* b2  = (const float*)d_in[15];
    const float* g2  = (const float*)d_in[16];
    const float* be2 = (const float*)d_in[17];
    const float* m2  = (const float*)d_in[18];
    const float* v2  = (const float*)d_in[19];
    float* out = (float*)d_out;

    char* wsp = (char*)d_ws;
    u16* xb   = (u16*)(wsp);
    u16* idwt = (u16*)(wsp + 16777216);
    u16* cat  = (u16*)(wsp + 16777216 + 67108864);
    u16* wf1  = (u16*)(wsp + 16777216 + 67108864 + 67108864);
    u16* wfS  = (u16*)(wsp + 16777216 + 67108864 + 67108864 + 1179648);
    u16* wf2  = (u16*)(wsp + 16777216 + 67108864 + 67108864 + 1179648 + 147456);

    cvt_fused_kernel<<<dim3(12288), dim3(256), 0, stream>>>(x, xb, s, cat);
    repack_fused_kernel<<<dim3(360), dim3(256), 0, stream>>>(w1, wsw, w2, wf1, wfS, wf2);

    conv1_mfma_kernel<<<dim3(32, 4, 16), dim3(256), 0, stream>>>(
        xb, wf1, b1, g1, be1, m1, v1, idwt);

    // convS + BN + ReLU -> cat chunks 2,3
    convg_mfma_kernel<false><<<dim3(128, 16), dim3(256), 0, stream>>>(
        idwt, wfS, bs, gs, bes, ms, vs,
        cat + (size_t)2 * 16 * 128 * 128 * 32, nullptr);

    // conv2 + BN + ReLU -> d_out (fp32 NCHW)
    convg_mfma_kernel<true><<<dim3(128, 16), dim3(256), 0, stream>>>(
        cat, wf2, b2, g2, be2, m2, v2, nullptr, out);
}

// Round 18
// 201.110 us; speedup vs baseline: 1.1297x; 1.1297x over previous
//
#include <hip/hip_runtime.h>
#include <hip/hip_bf16.h>

typedef __attribute__((ext_vector_type(8))) short short8;
typedef __attribute__((ext_vector_type(4))) float f32x4;
typedef unsigned short u16;

#define EPSV 1e-5f

__device__ __forceinline__ u16 f2bf(float f) {
    __hip_bfloat16 h = __float2bfloat16(f);
    return *reinterpret_cast<u16*>(&h);
}

#define GLOAD_LDS16(g, l)                                                      \
    __builtin_amdgcn_global_load_lds(                                          \
        (const __attribute__((address_space(1))) void*)(g),                    \
        (__attribute__((address_space(3))) void*)(l), 16, 0, 0)

// ---------------- fused NCHW fp32 -> [C/32][N][H][W][32] bf16 (x and s) ----------------
__global__ void cvt_fused_kernel(const float* __restrict__ x, u16* __restrict__ xb,
                                 const float* __restrict__ s, u16* __restrict__ sb) {
    int b = blockIdx.x;
    const float* src; u16* dst; int C, H, W, u;
    if (b < 4096) { src = x; dst = xb; C = 128; H = 64;  W = 64;  u = b * 256 + threadIdx.x; if (u >= 1048576) return; }
    else          { src = s; dst = sb; C = 64;  H = 128; W = 128; u = (b - 4096) * 256 + threadIdx.x; if (u >= 2097152) return; }
    int kb = u & 3;
    int p  = u >> 2;
    int xx = p % W;  p /= W;
    int yy = p % H;  p /= H;
    int n  = p & 15;
    int cc = p >> 4;
    short8 v;
#pragma unroll
    for (int j = 0; j < 8; ++j)
        v[j] = (short)f2bf(src[(((size_t)n * C + cc * 32 + kb * 8 + j) * H + yy) * W + xx]);
    *(short8*)(dst + ((((size_t)cc * 16 + n) * H + yy) * W + xx) * 32 + kb * 8) = v;
}

// ---------------- fused weight repack: fragment-linear (w1, ws, w2) ----------------
__global__ void repack_fused_kernel(const float* __restrict__ w1, const float* __restrict__ ws,
                                    const float* __restrict__ w2, u16* __restrict__ wf1,
                                    u16* __restrict__ wfS, u16* __restrict__ wf2) {
    int b = blockIdx.x;
    if (b < 288) {                            // w1: 4cc x 8bt x 9t x 4ciC x 64l
        int u = b * 256 + threadIdx.x;
        if (u >= 4 * 8 * 9 * 4 * 64) return;
        int l = u & 63;
        int r = u >> 6;
        int ciC = r & 3;  r >>= 2;
        int t   = r % 9;  r /= 9;
        int bt  = r & 7;
        int cc  = r >> 3;
        int co  = (bt >> 1) * 128 + cc * 32 + (bt & 1) * 16 + (l & 15);
        int ci0 = ciC * 32 + (l >> 4) * 8;
        short8 v;
#pragma unroll
        for (int e = 0; e < 8; ++e)
            v[e] = (short)f2bf(w1[((size_t)co * 128 + ci0 + e) * 9 + t]);
        *(short8*)(wf1 + (size_t)u * 8) = v;
    } else {                                  // ws / w2: 4bt x 9t x 4ciC x 64l
        int g = b - 288;                      // 0..71: g<36 -> ws, else w2
        const float* w = (g < 36) ? ws : w2;
        u16* wf        = (g < 36) ? wfS : wf2;
        int u = (g % 36) * 256 + threadIdx.x;
        if (u >= 4 * 9 * 4 * 64) return;
        int l = u & 63;
        int r = u >> 6;
        int ciC = r & 3;  r >>= 2;
        int t   = r % 9;
        int bt  = r / 9;
        int co  = bt * 16 + (l & 15);
        int ci0 = ciC * 32 + (l >> 4) * 8;
        short8 v;
#pragma unroll
        for (int e = 0; e < 8; ++e)
            v[e] = (short)f2bf(w[((size_t)co * 128 + ci0 + e) * 9 + t]);
        *(short8*)(wf + (size_t)u * 8) = v;
    }
}

// ---------------- conv1 + BN + ReLU + Haar IDWT (MFMA, LDS weight staging) ----------------
// Round-10/13 proven config (~81us): counted-vmcnt weight dbuf; no setprio
// (R14 A/B: +1us regression). Do not re-add.
__global__ __launch_bounds__(256, 2)
void conv1_mfma_kernel(const u16* __restrict__ inb, const u16* __restrict__ wf,
                       const float* __restrict__ bb, const float* __restrict__ gg,
                       const float* __restrict__ bee, const float* __restrict__ mm,
                       const float* __restrict__ vv, u16* __restrict__ ob) {
    const int tile = blockIdx.x;              // 4x x 8y = 32
    const int cc   = blockIdx.y;              // 4 base-c chunks
    const int n    = blockIdx.z;
    const int x0   = (tile & 3) * 16;
    const int y0   = (tile >> 2) * 8;
    const int tid  = threadIdx.x;
    const int lane = tid & 63;
    const int wid  = tid >> 6;
    const int wm   = wid >> 1;
    const int wc   = wid & 1;
    const int kb   = lane >> 4;
    const int xl   = lane & 15;

    __shared__ float4 lds4[720];              // input: 10 x 18 x 32 bf16, swizzled
    __shared__ float4 wlds[2][1536];          // weights: [buf][(bt*3+dy)*64 + lane]
    const short8* ldsr  = (const short8*)lds4;
    const short8* wldsr = (const short8*)wlds;

    f32x4 acc[4][4];
#pragma unroll
    for (int j = 0; j < 4; ++j)
#pragma unroll
        for (int q = 0; q < 4; ++q) acc[j][q] = (f32x4){0.f, 0.f, 0.f, 0.f};

    float4 sreg[3];
    auto load_stage = [&](int ciC) {
#pragma unroll
        for (int p = 0; p < 3; ++p) {
            int e = p * 256 + tid;
            float4 v = make_float4(0.f, 0.f, 0.f, 0.f);
            if (e < 720) {
                int pix = e >> 2, ke = e & 3;
                int yy = pix / 18;
                int xx = pix - yy * 18;
                int gy = y0 - 1 + yy, gx = x0 - 1 + xx;
                if ((unsigned)gy < 64u && (unsigned)gx < 64u)
                    v = *(const float4*)(inb + ((((size_t)ciC * 16 + n) * 64 + gy) * 64 + gx) * 32 + ke * 8);
            }
            sreg[p] = v;
        }
    };
    auto write_stage = [&]() {
#pragma unroll
        for (int p = 0; p < 3; ++p) {
            int e = p * 256 + tid;
            if (e < 720) lds4[e ^ ((e >> 2) & 7)] = sreg[p];
        }
    };
    auto stage_w = [&](int ciC, int dx, int buf) {
#pragma unroll
        for (int i = 0; i < 6; ++i) {
            int seg = wid * 6 + i;            // seg = bt*3 + dy
            int bt  = seg / 3;
            int dy  = seg - bt * 3;
            int t   = dy * 3 + dx;
            const u16* gp = wf + (size_t)((cc * 8 + bt) * 9 + t) * 2048 + ciC * 512 + lane * 8;
            GLOAD_LDS16(gp, &wlds[buf][seg * 64]);
        }
    };

    load_stage(0);
    stage_w(0, 0, 0);
    for (int ciC = 0; ciC < 4; ++ciC) {
        write_stage();
        asm volatile("s_waitcnt lgkmcnt(0)" ::: "memory");
        __builtin_amdgcn_s_barrier();
        __builtin_amdgcn_sched_barrier(0);
        if (ciC < 3) load_stage(ciC + 1);
#pragma unroll
        for (int dx = 0; dx < 3; ++dx) {
            const int cur = (ciC + dx) & 1;
            if (dx == 0) {
                if (ciC < 3) asm volatile("s_waitcnt vmcnt(3)" ::: "memory");
                else         asm volatile("s_waitcnt vmcnt(0)" ::: "memory");
            } else {
                asm volatile("s_waitcnt vmcnt(0)" ::: "memory");
            }
            __builtin_amdgcn_sched_barrier(0);
            __builtin_amdgcn_s_barrier();
            __builtin_amdgcn_sched_barrier(0);
            if (dx < 2)        stage_w(ciC, dx + 1, cur ^ 1);
            else if (ciC < 3)  stage_w(ciC + 1, 0, cur ^ 1);

            short8 a[6];
#pragma unroll
            for (int r = 0; r < 6; ++r) {
                int pix = (wm * 4 + r) * 18 + xl + dx;
                int e = pix * 4 + kb;
                a[r] = ldsr[e ^ ((e >> 2) & 7)];
            }
#pragma unroll
            for (int dy = 0; dy < 3; ++dy) {
                short8 b[4];
#pragma unroll
                for (int q = 0; q < 4; ++q) {
                    int bt = q * 2 + wc;
                    b[q] = wldsr[cur * 1536 + (bt * 3 + dy) * 64 + lane];
                }
#pragma unroll
                for (int j = 0; j < 4; ++j)
#pragma unroll
                    for (int q = 0; q < 4; ++q)
                        acc[j][q] = __builtin_amdgcn_mfma_f32_16x16x32_bf16(a[j + dy], b[q], acc[j][q], 0, 0, 0);
            }
        }
        __builtin_amdgcn_s_barrier();
    }

    float invq[4], shq[4];
#pragma unroll
    for (int q = 0; q < 4; ++q) {
        int co  = q * 128 + cc * 32 + wc * 16 + xl;
        float inv = gg[co] / sqrtf(vv[co] + EPSV);
        invq[q] = inv;
        shq[q]  = bb[co] * inv + bee[co] - mm[co] * inv;
    }
    const int c32 = wc * 16 + xl;
#pragma unroll
    for (int j = 0; j < 4; ++j) {
        int y = y0 + wm * 4 + j;
#pragma unroll
        for (int i = 0; i < 4; ++i) {
            float A_ = fmaxf(acc[j][0][i] * invq[0] + shq[0], 0.f);
            float H_ = fmaxf(acc[j][1][i] * invq[1] + shq[1], 0.f);
            float V_ = fmaxf(acc[j][2][i] * invq[2] + shq[2], 0.f);
            float D_ = fmaxf(acc[j][3][i] * invq[3] + shq[3], 0.f);
            float p00 = (A_ + H_ + V_ + D_) * 0.5f;
            float p01 = (A_ + H_ - V_ - D_) * 0.5f;
            float p10 = (A_ - H_ + V_ - D_) * 0.5f;
            float p11 = (A_ - H_ - V_ + D_) * 0.5f;
            int oy = 2 * y, ox = 2 * (x0 + kb * 4 + i);
            size_t base = ((((size_t)cc * 16 + n) * 128 + oy) * 128 + ox) * 32 + c32;
            ob[base]            = f2bf(p00);
            ob[base + 32]       = f2bf(p01);
            ob[base + 128 * 32] = f2bf(p10);
            ob[base + 128 * 32 + 32] = f2bf(p11);
        }
    }
}

// ---------------- generic 128ci -> 64co conv + BN + ReLU (MFMA), H=W=128 ----------------
// Round-12 proven form (best convg measured ~54.5us each): 16x16x32 MFMA,
// acc[4][2] = 8 independent chains, JIT weights from L2 (compiler pipelines
// B-loads across the dx loop), simple __syncthreads.
// 32x32x16 variant (R17): correct but -19us — only 2 acc chains serialize the
// matrix pipe + 2x B-load redundancy. Do not revisit.
template <bool FP32OUT>
__global__ __launch_bounds__(256, 2)
void convg_mfma_kernel(const u16* __restrict__ inb, const u16* __restrict__ wf,
                       const float* __restrict__ bb, const float* __restrict__ gg,
                       const float* __restrict__ bee, const float* __restrict__ mm,
                       const float* __restrict__ vv, u16* __restrict__ ob,
                       float* __restrict__ of) {
    const int tile = blockIdx.x;              // 8x x 16y = 128
    const int n    = blockIdx.y;
    const int x0   = (tile & 7) * 16;
    const int y0   = (tile >> 3) * 8;
    const int tid  = threadIdx.x;
    const int lane = tid & 63;
    const int wid  = tid >> 6;
    const int wm   = wid >> 1;                // y half (rows wm*4..wm*4+3)
    const int wc   = wid & 1;                 // co half (32 co)
    const int kb   = lane >> 4;
    const int xl   = lane & 15;

    __shared__ float4 lds4[720];              // 10 x 18 x 32 bf16, swizzled
    const short8* ldsr = (const short8*)lds4;

    f32x4 acc[4][2];                          // [row j][co16-tile cb]
#pragma unroll
    for (int j = 0; j < 4; ++j)
#pragma unroll
        for (int cb = 0; cb < 2; ++cb) acc[j][cb] = (f32x4){0.f, 0.f, 0.f, 0.f};

    float4 sreg[3];
    auto load_stage = [&](int ciC) {
#pragma unroll
        for (int p = 0; p < 3; ++p) {
            int e = p * 256 + tid;
            float4 v = make_float4(0.f, 0.f, 0.f, 0.f);
            if (e < 720) {
                int pix = e >> 2, ke = e & 3;
                int yy = pix / 18;
                int xx = pix - yy * 18;
                int gy = y0 - 1 + yy, gx = x0 - 1 + xx;
                if ((unsigned)gy < 128u && (unsigned)gx < 128u)
                    v = *(const float4*)(inb + ((((size_t)ciC * 16 + n) * 128 + gy) * 128 + gx) * 32 + ke * 8);
            }
            sreg[p] = v;
        }
    };
    auto write_stage = [&]() {
#pragma unroll
        for (int p = 0; p < 3; ++p) {
            int e = p * 256 + tid;
            if (e < 720) lds4[e ^ ((e >> 2) & 7)] = sreg[p];
        }
    };

    load_stage(0);
    for (int ciC = 0; ciC < 4; ++ciC) {
        write_stage();
        __syncthreads();
        if (ciC < 3) load_stage(ciC + 1);
#pragma unroll
        for (int dx = 0; dx < 3; ++dx) {
            short8 a[6];
#pragma unroll
            for (int r = 0; r < 6; ++r) {
                int pix = (wm * 4 + r) * 18 + xl + dx;
                int e = pix * 4 + kb;
                a[r] = ldsr[e ^ ((e >> 2) & 7)];
            }
#pragma unroll
            for (int dy = 0; dy < 3; ++dy) {
                const int t = dy * 3 + dx;
                short8 b[2];
#pragma unroll
                for (int cb = 0; cb < 2; ++cb) {
                    int bt = wc * 2 + cb;
                    b[cb] = *(const short8*)(wf + ((size_t)((bt * 9 + t) * 4 + ciC) * 64 + lane) * 8);
                }
#pragma unroll
                for (int j = 0; j < 4; ++j)
#pragma unroll
                    for (int cb = 0; cb < 2; ++cb)
                        acc[j][cb] = __builtin_amdgcn_mfma_f32_16x16x32_bf16(a[j + dy], b[cb], acc[j][cb], 0, 0, 0);
            }
        }
        __syncthreads();
    }

#pragma unroll
    for (int cb = 0; cb < 2; ++cb) {
        int co = (wc * 2 + cb) * 16 + xl;
        float inv = gg[co] / sqrtf(vv[co] + EPSV);
        float sh  = bb[co] * inv + bee[co] - mm[co] * inv;
#pragma unroll
        for (int j = 0; j < 4; ++j) {
            int y = y0 + wm * 4 + j;
            if (FP32OUT) {
                float4 v4;
                v4.x = fmaxf(acc[j][cb][0] * inv + sh, 0.f);
                v4.y = fmaxf(acc[j][cb][1] * inv + sh, 0.f);
                v4.z = fmaxf(acc[j][cb][2] * inv + sh, 0.f);
                v4.w = fmaxf(acc[j][cb][3] * inv + sh, 0.f);
                *(float4*)&of[(((size_t)n * 64 + co) * 128 + y) * 128 + x0 + kb * 4] = v4;
            } else {
#pragma unroll
                for (int i = 0; i < 4; ++i) {
                    float val = fmaxf(acc[j][cb][i] * inv + sh, 0.f);
                    int xg = x0 + kb * 4 + i;
                    ob[((((size_t)(co >> 5) * 16 + n) * 128 + y) * 128 + xg) * 32 + (co & 31)] = f2bf(val);
                }
            }
        }
    }
}

extern "C" void kernel_launch(void* const* d_in, const int* in_sizes, int n_in,
                              void* d_out, int out_size, void* d_ws, size_t ws_size,
                              hipStream_t stream) {
    const float* x   = (const float*)d_in[0];
    const float* s   = (const float*)d_in[1];
    const float* w1  = (const float*)d_in[2];
    const float* b1  = (const float*)d_in[3];
    const float* g1  = (const float*)d_in[4];
    const float* be1 = (const float*)d_in[5];
    const float* m1  = (const float*)d_in[6];
    const float* v1  = (const float*)d_in[7];
    const float* wsw = (const float*)d_in[8];
    const float* bs  = (const float*)d_in[9];
    const float* gs  = (const float*)d_in[10];
    const float* bes = (const float*)d_in[11];
    const float* ms  = (const float*)d_in[12];
    const float* vs  = (const float*)d_in[13];
    const float* w2  = (const float*)d_in[14];
    const float* b2  = (const float*)d_in[15];
    const float* g2  = (const float*)d_in[16];
    const float* be2 = (const float*)d_in[17];
    const float* m2  = (const float*)d_in[18];
    const float* v2  = (const float*)d_in[19];
    float* out = (float*)d_out;

    char* wsp = (char*)d_ws;
    u16* xb   = (u16*)(wsp);
    u16* idwt = (u16*)(wsp + 16777216);
    u16* cat  = (u16*)(wsp + 16777216 + 67108864);
    u16* wf1  = (u16*)(wsp + 16777216 + 67108864 + 67108864);
    u16* wfS  = (u16*)(wsp + 16777216 + 67108864 + 67108864 + 1179648);
    u16* wf2  = (u16*)(wsp + 16777216 + 67108864 + 67108864 + 1179648 + 147456);

    cvt_fused_kernel<<<dim3(12288), dim3(256), 0, stream>>>(x, xb, s, cat);
    repack_fused_kernel<<<dim3(360), dim3(256), 0, stream>>>(w1, wsw, w2, wf1, wfS, wf2);

    conv1_mfma_kernel<<<dim3(32, 4, 16), dim3(256), 0, stream>>>(
        xb, wf1, b1, g1, be1, m1, v1, idwt);

    // convS + BN + ReLU -> cat chunks 2,3
    convg_mfma_kernel<false><<<dim3(128, 16), dim3(256), 0, stream>>>(
        idwt, wfS, bs, gs, bes, ms, vs,
        cat + (size_t)2 * 16 * 128 * 128 * 32, nullptr);

    // conv2 + BN + ReLU -> d_out (fp32 NCHW)
    convg_mfma_kernel<true><<<dim3(128, 16), dim3(256), 0, stream>>>(
        cat, wf2, b2, g2, be2, m2, v2, nullptr, out);
}